// Round 2
// baseline (188.786 us; speedup 1.0000x reference)
//
#include <hip/hip_runtime.h>

// SecureOptimizedBlockReLU (16,128,114,114) fp32 — persistent grid-stride version.
// ch 0-31 passthrough copy; ch 32-79 2x2 block sign; ch 80-127 4x4 (block row/col
// 28 are 2-wide at the 114 edge). sign = f32_block_sum > -1.0f, summed in the
// exact row-major sequential order verified bit-exact R1-R6 (absmax 0.0).
//
// Evidence trail: R6 strip-LDS (65 us) and R7 one-shot register kernel (66 us)
// are IDENTICAL despite removing LDS+barriers+div/mod -> bottleneck is neither.
// Both used one-shot waves: ~20 setup VALU, 1-2 dependent loads, full-latency
// wait, store, die. MLP per wave ~1 KB, wave-launch overhead x92k waves.
// This version: 2048 persistent blocks (8/CU exactly), each wave grid-strides
// over many units with manual unroll so ~8 independent vector loads stay in
// flight continuously (the structure fill/copy ubenches use to hit 6.3+ TB/s).
// Class split by byte share: A=512 blocks (25%), B=768, C=768 (37.5% each).
// NOTE: rows are 456 B apart (8 mod 16) -> float2 accesses for classes B/C.

typedef float v4 __attribute__((ext_vector_type(4)));

#define PLANE     12996     // 114*114 floats
#define NA4       1663488   // class-A float4 total: 16 * 103968
#define A_PER_N   103968    // 32*12996/4 float4 per n
#define A_NSTRIDE 415872    // 128*12996/4 float4 per n
#define NB_A      512
#define NB_B      768
#define NB_C      768
#define SW_B      3072      // NB_B*4 class-B waves
#define SW_C      3072      // NB_C*4 class-C waves
#define NU_B      43776     // 768 planes * 57 row-pairs
#define NU_C      22272     // 768 planes * 29 block-rows
#define NPAIR_C   11136     // NU_C/2

__device__ __forceinline__ int amap(int idx) {
    int n = idx / A_PER_N;
    return n * A_NSTRIDE + (idx - n * A_PER_N);
}

__device__ __forceinline__ size_t bbase(int u) {
    int p  = u / 57;
    int rp = u - 57 * p;
    int n  = p / 48;
    int c  = 32 + (p - 48 * n);
    return (size_t)(n * 128 + c) * PLANE + 228 * rp;
}

// one 2x2 row-pair unit: lane covers cols 2*lane, 2*lane+1; rows 2rp, 2rp+1
__device__ __forceinline__ void bproc1(const float* __restrict__ in,
                                       float* __restrict__ out,
                                       int u, int lane) {
    size_t b = bbase(u);
    const float2* ip = (const float2*)(in + b) + lane;
    float2 a = ip[0], c = ip[57];
    float s = ((a.x + a.y) + c.x) + c.y;          // exact R1-R6 order
    float m = (s > -1.0f) ? 1.0f : 0.0f;
    float2* op = (float2*)(out + b) + lane;
    op[0]  = make_float2(a.x * m, a.y * m);
    op[57] = make_float2(c.x * m, c.y * m);
}

// one 4x4 block: lane param cb = block-col 0..28
__device__ __forceinline__ void cproc1(const float* __restrict__ in,
                                       float* __restrict__ out,
                                       int u, int cb) {
    int p  = u / 29;
    int br = u - 29 * p;
    int n  = p / 48;
    int c  = 80 + (p - 48 * n);
    size_t base = (size_t)(n * 128 + c) * PLANE + 456 * br;
    const bool full = (cb != 28);                 // block-col 28 is 2 cols wide
    const float2* q  = (const float2*)(in  + base) + 2 * cb;
    float2*       qo = (float2*)      (out + base) + 2 * cb;

    if (br != 28) {
        float2 a0 = q[0],  a1 = q[57],  a2 = q[114], a3 = q[171];
        float2 b0 = make_float2(0.f, 0.f), b1 = b0, b2 = b0, b3 = b0;
        if (full) { b0 = q[1]; b1 = q[58]; b2 = q[115]; b3 = q[172]; }
        float s = 0.0f;                           // row-major sequential
        s += a0.x; s += a0.y; if (full) { s += b0.x; s += b0.y; }
        s += a1.x; s += a1.y; if (full) { s += b1.x; s += b1.y; }
        s += a2.x; s += a2.y; if (full) { s += b2.x; s += b2.y; }
        s += a3.x; s += a3.y; if (full) { s += b3.x; s += b3.y; }
        float m = (s > -1.0f) ? 1.0f : 0.0f;
        qo[0]   = make_float2(a0.x * m, a0.y * m);
        qo[57]  = make_float2(a1.x * m, a1.y * m);
        qo[114] = make_float2(a2.x * m, a2.y * m);
        qo[171] = make_float2(a3.x * m, a3.y * m);
        if (full) {
            qo[1]   = make_float2(b0.x * m, b0.y * m);
            qo[58]  = make_float2(b1.x * m, b1.y * m);
            qo[115] = make_float2(b2.x * m, b2.y * m);
            qo[172] = make_float2(b3.x * m, b3.y * m);
        }
    } else {                                      // rows 112..113 only
        float2 a0 = q[0], a1 = q[57];
        float2 b0 = make_float2(0.f, 0.f), b1 = b0;
        if (full) { b0 = q[1]; b1 = q[58]; }
        float s = 0.0f;
        s += a0.x; s += a0.y; if (full) { s += b0.x; s += b0.y; }
        s += a1.x; s += a1.y; if (full) { s += b1.x; s += b1.y; }
        float m = (s > -1.0f) ? 1.0f : 0.0f;
        qo[0]  = make_float2(a0.x * m, a0.y * m);
        qo[57] = make_float2(a1.x * m, a1.y * m);
        if (full) {
            qo[1]  = make_float2(b0.x * m, b0.y * m);
            qo[58] = make_float2(b1.x * m, b1.y * m);
        }
    }
}

__global__ __launch_bounds__(256) void sbrelu_ps(const float* __restrict__ in,
                                                 float* __restrict__ out) {
    const int bid  = blockIdx.x;
    const int tid  = threadIdx.x;
    const int lane = tid & 63;
    const int wid  = tid >> 6;

    if (bid < NB_A) {
        // ---- class A: ch 0..31 float4 copy, 4 independent load/stores per iter ----
        const v4* __restrict__ vin = (const v4*)in;
        v4* __restrict__ vout = (v4*)out;
        const int t = bid * 256 + tid;            // [0, 131072)
        const int S = NB_A * 256;                 // 131072
        // NA4 = 12*S + 90624: three unrolled quads then one conditional single
        for (int base = 0; base < 12 * S; base += 4 * S) {
            int o0 = amap(t + base);
            int o1 = amap(t + base + S);
            int o2 = amap(t + base + 2 * S);
            int o3 = amap(t + base + 3 * S);
            v4 x0 = vin[o0], x1 = vin[o1], x2 = vin[o2], x3 = vin[o3];
            vout[o0] = x0; vout[o1] = x1; vout[o2] = x2; vout[o3] = x3;
        }
        int jt = t + 12 * S;
        if (jt < NA4) { int o = amap(jt); vout[o] = vin[o]; }
        return;
    }

    if (bid < NB_A + NB_B) {
        // ---- class B: 2x2. Persistent wave, 4 units unrolled (8 loads in flight) ----
        if (lane >= 57) return;
        const int wb = (bid - NB_A) * 4 + wid;    // [0, 3072)
        // NU_B = 14*SW_B + 768: 3 quads + 1 pair + conditional single
        for (int k = 0; k < 12; k += 4) {
            int u0 = wb + (k    ) * SW_B;
            int u1 = wb + (k + 1) * SW_B;
            int u2 = wb + (k + 2) * SW_B;
            int u3 = wb + (k + 3) * SW_B;
            size_t e0 = bbase(u0), e1 = bbase(u1), e2 = bbase(u2), e3 = bbase(u3);
            const float2* p0 = (const float2*)(in + e0) + lane;
            const float2* p1 = (const float2*)(in + e1) + lane;
            const float2* p2 = (const float2*)(in + e2) + lane;
            const float2* p3 = (const float2*)(in + e3) + lane;
            float2 a0 = p0[0], c0 = p0[57];
            float2 a1 = p1[0], c1 = p1[57];
            float2 a2 = p2[0], c2 = p2[57];
            float2 a3 = p3[0], c3 = p3[57];
            float s0 = ((a0.x + a0.y) + c0.x) + c0.y;
            float s1 = ((a1.x + a1.y) + c1.x) + c1.y;
            float s2 = ((a2.x + a2.y) + c2.x) + c2.y;
            float s3 = ((a3.x + a3.y) + c3.x) + c3.y;
            float m0 = (s0 > -1.0f) ? 1.0f : 0.0f;
            float m1 = (s1 > -1.0f) ? 1.0f : 0.0f;
            float m2 = (s2 > -1.0f) ? 1.0f : 0.0f;
            float m3 = (s3 > -1.0f) ? 1.0f : 0.0f;
            float2* q0 = (float2*)(out + e0) + lane;
            float2* q1 = (float2*)(out + e1) + lane;
            float2* q2 = (float2*)(out + e2) + lane;
            float2* q3 = (float2*)(out + e3) + lane;
            q0[0] = make_float2(a0.x * m0, a0.y * m0); q0[57] = make_float2(c0.x * m0, c0.y * m0);
            q1[0] = make_float2(a1.x * m1, a1.y * m1); q1[57] = make_float2(c1.x * m1, c1.y * m1);
            q2[0] = make_float2(a2.x * m2, a2.y * m2); q2[57] = make_float2(c2.x * m2, c2.y * m2);
            q3[0] = make_float2(a3.x * m3, a3.y * m3); q3[57] = make_float2(c3.x * m3, c3.y * m3);
        }
        bproc1(in, out, wb + 12 * SW_B, lane);
        bproc1(in, out, wb + 13 * SW_B, lane);
        int u = wb + 14 * SW_B;
        if (u < NU_B) bproc1(in, out, u, lane);
        return;
    }

    // ---- class C: 4x4. Two block-rows per wave (half-waves), 8 loads/unit ----
    const int cb = lane & 31;
    if (cb >= 29) return;
    const int wc = (bid - NB_A - NB_B) * 4 + wid; // [0, 3072)
    const int half = lane >> 5;                   // 0 or 1
    // NPAIR_C = 3*SW_C + 1920: 3 full iterations + conditional 4th
    for (int k = 0; k < 4; ++k) {
        int pr = k * SW_C + wc;                   // pair id
        if (pr >= NPAIR_C) break;
        cproc1(in, out, 2 * pr + half, cb);
    }
}

extern "C" void kernel_launch(void* const* d_in, const int* in_sizes, int n_in,
                              void* d_out, int out_size, void* d_ws, size_t ws_size,
                              hipStream_t stream) {
    const float* in = (const float*)d_in[0];
    float* out = (float*)d_out;
    sbrelu_ps<<<NB_A + NB_B + NB_C, 256, 0, stream>>>(in, out);
}